// Round 8
// baseline (985.260 us; speedup 1.0000x reference)
//
#include <hip/hip_runtime.h>
#include <hip/hip_bf16.h>

#define B_ 2048
#define T_ 512
#define DIN_ 32
#define DH_ 96
#define NG_ 384
#define E_ 6

#define BPB 8      // batch rows per block
#define HP 104     // fp16 elems per h row (96 + 8 pad, keeps 16B alignment)
#define GS 12      // dwords per sgate row: 48B rows -> 16B-aligned b128 gate
                   // stores; write & read bank patterns both exactly 2-way (free)

typedef __attribute__((ext_vector_type(8))) _Float16 f16x8;
typedef __attribute__((ext_vector_type(4))) float f32x4;

#if defined(__has_builtin)
# if __has_builtin(__builtin_amdgcn_exp2f)
#  define EXP2F(x) __builtin_amdgcn_exp2f(x)
# endif
# if __has_builtin(__builtin_amdgcn_rcpf)
#  define RCPF(x) __builtin_amdgcn_rcpf(x)
# endif
#endif
#ifndef EXP2F
# define EXP2F(x) exp2f(x)
#endif
#ifndef RCPF
# define RCPF(x) (1.0f/(x))
#endif

__device__ __forceinline__ float sigf(float x) {
    return RCPF(1.0f + EXP2F(x * -1.44269504f));
}
__device__ __forceinline__ float tanhf_(float x) {
    return 1.0f - 2.0f * RCPF(1.0f + EXP2F(x * 2.88539008f));
}

__device__ __forceinline__ f16x8 cvt8(float4 a, float4 b) {
    f16x8 r;
    r[0] = (_Float16)a.x; r[1] = (_Float16)a.y; r[2] = (_Float16)a.z; r[3] = (_Float16)a.w;
    r[4] = (_Float16)b.x; r[5] = (_Float16)b.y; r[6] = (_Float16)b.z; r[7] = (_Float16)b.w;
    return r;
}
__device__ __forceinline__ f16x8 cvt8p(const float* p) {
    return cvt8(*(const float4*)p, *(const float4*)(p + 4));
}

// LDS-only barrier: waits lgkmcnt(0) but NOT vmcnt (outstanding global stores
// don't serialize the recurrence).
__device__ __forceinline__ void lds_barrier() {
    asm volatile("s_waitcnt lgkmcnt(0)\n\ts_barrier" ::: "memory");
}

// ---------------- sort kernel: counting sort of batches by length -----------
__global__ __launch_bounds__(512) void sort_kernel(
    const int* __restrict__ lengths, int* __restrict__ perm) {
    __shared__ int sbins[512];
    __shared__ int soffs[512];
    const int tid = threadIdx.x;
    sbins[tid] = 0;
    __syncthreads();
    for (int b = tid; b < B_; b += 512) atomicAdd(&sbins[lengths[b] - 1], 1);
    __syncthreads();
    soffs[tid] = sbins[tid];
    __syncthreads();
    for (int d = 1; d < 512; d <<= 1) {
        int v = (tid >= d) ? soffs[tid - d] : 0;
        __syncthreads();
        soffs[tid] += v;
        __syncthreads();
    }
    int excl = soffs[tid] - sbins[tid];   // exclusive prefix
    __syncthreads();
    soffs[tid] = excl;
    __syncthreads();
    for (int b = tid; b < B_; b += 512) {
        const int pos = atomicAdd(&soffs[lengths[b] - 1], 1);
        perm[pos] = b;
    }
}

// ---------------- Kernel A: fused LSTM (measured-best structure + trims) ----
// 256 blocks x 768 threads (12 waves). Block owns 8 length-sorted batch rows.
// Phase 1: wave w computes gate-tiles {2w,2w+1}; A rows 8-15 are ZEROS via
//   exec-masked (col<8) LDS reads + v_mov zeros. x prefetch masked to col<8.
//   Gate store: single ds_write_b128 (GS=12 keeps rows 16B-aligned).
// Phase 3' (after barrier1, overlaps phase2): coop-store h(t-1) LDS->global.
// Phase 2: lane -> (u,b) reads i/f/g/o from sgate, activations, writes fp16 h;
//   then converts NEXT step's x (load ~1 interval old -> latency hidden, and
//   the cvt chain is off phase-1's pre-MFMA critical path).
// NOTE (measured): restructures all lose — register-local epilogue 646-751us,
//   2-slot batch-split pipeline 996us, vs this structure's ~449us.
__global__ __launch_bounds__(768, 1) void lstm_kernel(
    const float* __restrict__ x, const int* __restrict__ lengths,
    const int* __restrict__ perm,
    const float* __restrict__ Wih, const float* __restrict__ Whh,
    const float* __restrict__ bih, const float* __restrict__ bhh,
    _Float16* __restrict__ Hout, float* __restrict__ hT)
{
    __shared__ float sgate[NG_ * GS];       // raw gates [gcol][b], 18432 B
    __shared__ _Float16 sh[2][8 * HP];      // h double buffer [b][u], 8 real rows
    __shared__ int sgb[BPB], slen[BPB];

    const int tid  = threadIdx.x;
    const int bb   = blockIdx.x * BPB;
    const int wave = tid >> 6;
    const int lane = tid & 63;
    const int col  = lane & 15;
    const int quad = lane >> 4;

    if (tid < BPB) {
        const int g = perm[bb + tid];
        sgb[tid] = g;
        slen[tid] = lengths[g];
    }
    // zero h buffers
    {
        _Float16* shf = &sh[0][0];
        for (int i = tid; i < 2 * 8 * HP; i += 768) shf[i] = (_Float16)0.f;
    }
    __syncthreads();

    int bmax = slen[0];
#pragma unroll
    for (int i = 1; i < BPB; ++i) bmax = max(bmax, slen[i]);

    // ---- MFMA role: 2 gate tiles per wave
    int gc[2];
    f32x4 bias4[2];                   // vector bias init (no per-step splats)
    f16x8 wh[2][3], wi[2];
#pragma unroll
    for (int j = 0; j < 2; ++j) {
        const int tau = wave * 2 + j;
        const int g = tau / 6, u6 = tau % 6;
        const int gcj = g * DH_ + u6 * 16 + col;
        gc[j] = gcj;
#pragma unroll
        for (int kf = 0; kf < 3; ++kf)
            wh[j][kf] = cvt8p(Whh + gcj * DH_ + kf * 32 + quad * 8);
        wi[j] = cvt8p(Wih + gcj * DIN_ + quad * 8);
        const float bj = bih[gcj] + bhh[gcj];
        bias4[j] = f32x4{bj, bj, bj, bj};
    }

    // ---- epilogue role: one (unit, batch) pair per lane
    const int eu = tid >> 3;          // 0..95
    const int eb = tid & 7;           // 0..7
    float c1 = 0.f, hk1 = 0.f;
    const int len1 = slen[eb];

    // ---- coop-store role
    const bool st_act = tid < 384;
    const int sb = tid / 48;                  // batch row 0..7
    const int su = (tid % 48) * 2;            // unit pair
    _Float16* Hst = Hout + ((long long)sgb[sb] * T_) * DH_ + su;

    // ---- x prefetch, masked to the 8 real A rows; x(0) converted up front
    const bool arow = col < 8;
    const float* xp = x + ((long long)sgb[col & 7] * T_) * DIN_ + quad * 8;
    f16x8 xa = 0;
    if (arow) xa = cvt8(*(const float4*)xp, *(const float4*)(xp + 4));

    for (int t = 0; t < bmax; ++t) {
        const int buf = t & 1;

        // ---------- phase 1: MFMA (all waves) ----------
        // A rows 8-15 are zeros: masked read, lanes col>=8 keep v_mov zeros.
        f16x8 h0 = 0, h1 = 0, h2 = 0;
        if (arow) {
            const _Float16* hrow = &sh[buf][col * HP];
            h0 = *(const f16x8*)(hrow + 0  + quad * 8);
            h1 = *(const f16x8*)(hrow + 32 + quad * 8);
            h2 = *(const f16x8*)(hrow + 64 + quad * 8);
        }

        // prefetch x(t+1), masked (converted in phase 2, off critical path)
        const float* xpn = (t + 1 < T_) ? (xp + DIN_) : xp;
        float4 xn0 = make_float4(0.f, 0.f, 0.f, 0.f), xn1 = xn0;
        if (arow) { xn0 = *(const float4*)xpn; xn1 = *(const float4*)(xpn + 4); }

#pragma unroll
        for (int j = 0; j < 2; ++j) {
            f32x4 a = bias4[j];
            a = __builtin_amdgcn_mfma_f32_16x16x32_f16(h0, wh[j][0], a, 0, 0, 0);
            a = __builtin_amdgcn_mfma_f32_16x16x32_f16(h1, wh[j][1], a, 0, 0, 0);
            a = __builtin_amdgcn_mfma_f32_16x16x32_f16(h2, wh[j][2], a, 0, 0, 0);
            a = __builtin_amdgcn_mfma_f32_16x16x32_f16(xa, wi[j],    a, 0, 0, 0);
            if (quad < 2)   // D rows 0-7 real batch; single 16B-aligned store
                *(f32x4*)&sgate[gc[j] * GS + quad * 4] = a;
        }
        lds_barrier();   // gates visible (also orders prev step's h writes)

        // ---------- phase 3': coop-store h(t-1), overlaps phase 2 ----------
        if (t > 0 && st_act) {
            unsigned v = *(const unsigned*)&sh[buf][sb * HP + su];
            *(unsigned*)Hst = v;
            Hst += DH_;
        }

        // ---------- phase 2: epilogue (one pair per lane) ----------
        {
            float iv = sgate[(0 * DH_ + eu) * GS + eb];
            float fv = sgate[(1 * DH_ + eu) * GS + eb];
            float gv = sgate[(2 * DH_ + eu) * GS + eb];
            float ov = sgate[(3 * DH_ + eu) * GS + eb];
            float cn = sigf(fv) * c1 + sigf(iv) * tanhf_(gv);
            float hn = sigf(ov) * tanhf_(cn);
            const bool m = t < len1;
            c1  = m ? cn : c1;
            hk1 = m ? hn : hk1;
            sh[buf ^ 1][eb * HP + eu] = (_Float16)hk1;
        }

        // convert x(t+1) here: load is ~a full interval old (hidden), and the
        // cvt chain stays out of next phase-1's pre-MFMA path. Zeros stay 0.
        xa = cvt8(xn0, xn1);

        lds_barrier();   // h(t) visible

        xp = xpn;
    }

    // final H column t = bmax-1
    if (st_act) {
        unsigned v = *(const unsigned*)&sh[bmax & 1][sb * HP + su];
        *(unsigned*)Hst = v;
    }

    hT[sgb[eb] * DH_ + eu] = hk1;
}

// ---------------- Kernel B: fused Q/qk + logits/softmax/ctx + MoE head -----
// One block per batch, 256 threads — MEASURED-BEST (round-5, ~249us tail).
// Register-hoisted-H variant measured ~+75us (VGPR/occupancy cost) — reverted.
__global__ __launch_bounds__(256) void attn_moe_kernel(
    const _Float16* __restrict__ H, const float* __restrict__ hT,
    const int* __restrict__ lengths,
    const float* __restrict__ Wq, const float* __restrict__ bq,
    const float* __restrict__ Wk, const float* __restrict__ bk,
    const float* __restrict__ Wv, const float* __restrict__ bv,
    const float* __restrict__ Wg, const float* __restrict__ bg,
    const float* __restrict__ We1, const float* __restrict__ be1,
    const float* __restrict__ We2, const float* __restrict__ be2,
    float* __restrict__ yhat_out, float* __restrict__ alpha_out,
    float* __restrict__ gl_out)
{
    __shared__ float salpha[T_];
    __shared__ float shT[DH_];
    __shared__ float sQ[DH_];
    __shared__ float sqk[DH_];
    __shared__ float spart[DH_];
    __shared__ float sfeats[2 * DH_];
    __shared__ float sh1[2][DH_];
    __shared__ float sred[4], ssum[4];
    __shared__ float sgl[E_];
    __shared__ float spi[2];
    __shared__ float souts[2];
    __shared__ float sqb_s;
    __shared__ int stopi[2];

    const int b = blockIdx.x, tid = threadIdx.x;
    const int len = lengths[b];
    const float scale = 0.10206207262f; // 1/sqrt(96)

    // ---- fused qk: Q = Wq@hT + bq; qk = (Wk^T Q)*scale; qb = (Q.bk)*scale
    if (tid < DH_) shT[tid] = hT[b * DH_ + tid];
    __syncthreads();
    if (tid < DH_) {
        float acc = bq[tid];
        const float* wr = Wq + tid * DH_;
        for (int d = 0; d < DH_; d += 4) {
            float4 w4 = *(const float4*)(wr + d);
            acc += w4.x * shT[d] + w4.y * shT[d + 1] + w4.z * shT[d + 2] + w4.w * shT[d + 3];
        }
        sQ[tid] = acc;
    }
    __syncthreads();
    if (tid < DH_) {
        float acc = 0.f;
        for (int j = 0; j < DH_; ++j) acc += Wk[j * DH_ + tid] * sQ[j];
        sqk[tid] = acc * scale;
    }
    if (tid >= 192) {                 // wave 3 computes qb in parallel
        const int ln = tid - 192;
        float p = sQ[ln] * bk[ln];
        if (ln < DH_ - 64) p += sQ[ln + 64] * bk[ln + 64];
        for (int off = 32; off; off >>= 1) p += __shfl_xor(p, off);
        if (ln == 0) sqb_s = p * scale;
    }
    __syncthreads();
    const float qbv = sqb_s;

    // logits: 2 t's per thread (t = tid, tid+256)
    float lg[2]; bool vd[2];
#pragma unroll
    for (int hh = 0; hh < 2; ++hh) {
        const int t = tid + hh * 256;
        vd[hh] = t < len;
        float l = qbv;
        if (vd[hh]) {
            const _Float16* hr = H + ((long long)b * T_ + t) * DH_;
#pragma unroll
            for (int u = 0; u < DH_; u += 8) {
                f16x8 hv = *(const f16x8*)(hr + u);
                float4 qa = *(const float4*)&sqk[u];
                float4 qc = *(const float4*)&sqk[u + 4];
                l += (float)hv[0] * qa.x + (float)hv[1] * qa.y
                   + (float)hv[2] * qa.z + (float)hv[3] * qa.w
                   + (float)hv[4] * qc.x + (float)hv[5] * qc.y
                   + (float)hv[6] * qc.z + (float)hv[7] * qc.w;
            }
        }
        lg[hh] = l;
    }

    float m = fmaxf(vd[0] ? lg[0] : -1e30f, vd[1] ? lg[1] : -1e30f);
    for (int off = 32; off; off >>= 1) m = fmaxf(m, __shfl_xor(m, off));
    if ((tid & 63) == 0) sred[tid >> 6] = m;
    __syncthreads();
    m = fmaxf(fmaxf(sred[0], sred[1]), fmaxf(sred[2], sred[3]));

    float e0 = vd[0] ? EXP2F((lg[0] - m) * 1.44269504f) : 0.f;
    float e1 = vd[1] ? EXP2F((lg[1] - m) * 1.44269504f) : 0.f;
    float s = e0 + e1;
    for (int off = 32; off; off >>= 1) s += __shfl_xor(s, off);
    if ((tid & 63) == 0) ssum[tid >> 6] = s;
    __syncthreads();
    s = (ssum[0] + ssum[1]) + (ssum[2] + ssum[3]);

    const float rinv = RCPF(s);
    const float a0 = e0 * rinv, a1 = e1 * rinv;
    salpha[tid] = a0;
    salpha[tid + 256] = a1;
    alpha_out[(long long)b * T_ + tid] = a0;
    alpha_out[(long long)b * T_ + tid + 256] = a1;
    __syncthreads();

    // ctx raw: 12 u-blocks x 16 t-lanes, f16x8 loads, shfl-tree reduce over tl
    if (tid < 192) {
        const int ub = tid >> 4, tl = tid & 15;
        float acc[8] = {0.f, 0.f, 0.f, 0.f, 0.f, 0.f, 0.f, 0.f};
        const _Float16* hb = H + ((long long)b * T_) * DH_ + ub * 8;
#pragma unroll 4
        for (int k = 0; k < 32; ++k) {
            const int t = tl + (k << 4);
            if (t < len) {
                f16x8 hv = *(const f16x8*)(hb + t * DH_);
                const float a = salpha[t];
#pragma unroll
                for (int i = 0; i < 8; ++i) acc[i] += a * (float)hv[i];
            }
        }
#pragma unroll
        for (int i = 0; i < 8; ++i) {
            acc[i] += __shfl_xor(acc[i], 1);
            acc[i] += __shfl_xor(acc[i], 2);
            acc[i] += __shfl_xor(acc[i], 4);
            acc[i] += __shfl_xor(acc[i], 8);
        }
        if (tl == 0) {
#pragma unroll
            for (int i = 0; i < 8; ++i) spart[ub * 8 + i] = acc[i];
        }
    }
    __syncthreads();

    // ctx = Wv @ craw + bv ; feats = [ctx, hT]
    if (tid < DH_) {
        float acc = bv[tid];
        const float* wr = Wv + tid * DH_;
        for (int u = 0; u < DH_; u += 4) {
            float4 w4 = *(const float4*)(wr + u);
            acc += w4.x * spart[u] + w4.y * spart[u + 1] + w4.z * spart[u + 2] + w4.w * spart[u + 3];
        }
        sfeats[tid] = acc;             // ctx
        sfeats[DH_ + tid] = shT[tid];  // hT (already in LDS)
    }
    __syncthreads();

    // gate logits: 6 experts x 32 lanes, 6 f-elems per lane
    if (tid < 192) {
        const int e6 = tid >> 5, cc = tid & 31;
        float p = 0.f;
        const float* wg = Wg + e6 * 2 * DH_;
#pragma unroll
        for (int j = 0; j < 6; ++j) p += wg[cc * 6 + j] * sfeats[cc * 6 + j];
        for (int off = 16; off; off >>= 1) p += __shfl_xor(p, off);
        if (cc == 0) {
            float g = p + bg[e6];
            sgl[e6] = g;
            gl_out[b * E_ + e6] = g;
        }
    }
    __syncthreads();

    if (tid == 0) {
        int i0 = 0; float v0 = sgl[0];
        for (int ee = 1; ee < E_; ++ee) if (sgl[ee] > v0) { v0 = sgl[ee]; i0 = ee; }
        int i1 = -1; float v1 = -1e30f;
        for (int ee = 0; ee < E_; ++ee) {
            if (ee == i0) continue;
            if (sgl[ee] > v1) { v1 = sgl[ee]; i1 = ee; }
        }
        float ex1 = EXP2F((v1 - v0) * 1.44269504f);
        float inv = RCPF(1.f + ex1);
        spi[0] = inv; spi[1] = ex1 * inv;
        stopi[0] = i0; stopi[1] = i1;
    }
    __syncthreads();

    // expert hidden for the 2 selected experts
    if (tid < 192) {
        const int e2 = tid / DH_, u = tid - e2 * DH_;
        const int ex = stopi[e2];
        float acc = be1[ex * DH_ + u];
        const float* w = We1 + ((long long)ex * DH_ + u) * (2 * DH_);
        for (int f = 0; f < 2 * DH_; f += 4) {
            float4 w4 = *(const float4*)(w + f);
            acc += w4.x * sfeats[f] + w4.y * sfeats[f + 1] + w4.z * sfeats[f + 2] + w4.w * sfeats[f + 3];
        }
        sh1[e2][u] = fmaxf(acc, 0.f);
    }
    __syncthreads();

    // final expert outputs: one wave per expert
    if (tid < 128) {
        const int e2 = tid >> 6, ln = tid & 63;
        const int ex = stopi[e2];
        const float* w2 = We2 + ex * DH_;
        float p = sh1[e2][ln] * w2[ln];
        if (ln < DH_ - 64) p += sh1[e2][ln + 64] * w2[ln + 64];
        for (int off = 32; off; off >>= 1) p += __shfl_xor(p, off);
        if (ln == 0) souts[e2] = p + be2[ex];
    }
    __syncthreads();
    if (tid == 0)
        yhat_out[b] = spi[0] * souts[0] + spi[1] * souts[1];
}

extern "C" void kernel_launch(void* const* d_in, const int* in_sizes, int n_in,
                              void* d_out, int out_size, void* d_ws, size_t ws_size,
                              hipStream_t stream) {
    const float* x   = (const float*)d_in[0];
    const int* lengths = (const int*)d_in[1];
    // d_in[2] = mask (recomputed from lengths)
    const float* Wih = (const float*)d_in[3];
    const float* Whh = (const float*)d_in[4];
    const float* bih = (const float*)d_in[5];
    const float* bhh = (const float*)d_in[6];
    const float* Wq  = (const float*)d_in[7];
    const float* bq  = (const float*)d_in[8];
    const float* Wk  = (const float*)d_in[9];
    const float* bk  = (const float*)d_in[10];
    const float* Wv  = (const float*)d_in[11];
    const float* bv  = (const float*)d_in[12];
    const float* Wg  = (const float*)d_in[13];
    const float* bg  = (const float*)d_in[14];
    const float* We1 = (const float*)d_in[15];
    const float* be1 = (const float*)d_in[16];
    const float* We2 = (const float*)d_in[17];
    const float* be2 = (const float*)d_in[18];

    float* yhat  = (float*)d_out;
    float* alpha = yhat + B_;
    float* gl    = alpha + (size_t)B_ * T_;

    char* ws = (char*)d_ws;
    _Float16* Hws = (_Float16*)ws;                                   // B*T*96 fp16
    float* hTws = (float*)(ws + (size_t)B_ * T_ * DH_ * 2);          // B*96 f32
    int* perm   = (int*)(hTws + (size_t)B_ * DH_);                   // B

    sort_kernel<<<dim3(1), dim3(512), 0, stream>>>(lengths, perm);

    lstm_kernel<<<dim3(B_ / BPB), dim3(768), 0, stream>>>(
        x, lengths, perm, Wih, Whh, bih, bhh, Hws, hTws);
    attn_moe_kernel<<<dim3(B_), dim3(256), 0, stream>>>(
        Hws, hTws, lengths, Wq, bq, Wk, bk, Wv, bv, Wg, bg,
        We1, be1, We2, be2, yhat, alpha, gl);
}

// Round 9
// 749.004 us; speedup vs baseline: 1.3154x; 1.3154x over previous
//
#include <hip/hip_runtime.h>
#include <hip/hip_bf16.h>

#define B_ 2048
#define T_ 512
#define DIN_ 32
#define DH_ 96
#define NG_ 384
#define E_ 6

#define BPB 8      // batch rows per block
#define HP 104     // fp16 elems per h row (96 + 8 pad, keeps 16B alignment)
#define GS 10      // dwords per sgate row

typedef __attribute__((ext_vector_type(8))) _Float16 f16x8;
typedef __attribute__((ext_vector_type(4))) float f32x4;

#if defined(__has_builtin)
# if __has_builtin(__builtin_amdgcn_exp2f)
#  define EXP2F(x) __builtin_amdgcn_exp2f(x)
# endif
# if __has_builtin(__builtin_amdgcn_rcpf)
#  define RCPF(x) __builtin_amdgcn_rcpf(x)
# endif
#endif
#ifndef EXP2F
# define EXP2F(x) exp2f(x)
#endif
#ifndef RCPF
# define RCPF(x) (1.0f/(x))
#endif

__device__ __forceinline__ float sigf(float x) {
    return RCPF(1.0f + EXP2F(x * -1.44269504f));
}
__device__ __forceinline__ float tanhf_(float x) {
    return 1.0f - 2.0f * RCPF(1.0f + EXP2F(x * 2.88539008f));
}

__device__ __forceinline__ f16x8 cvt8(float4 a, float4 b) {
    f16x8 r;
    r[0] = (_Float16)a.x; r[1] = (_Float16)a.y; r[2] = (_Float16)a.z; r[3] = (_Float16)a.w;
    r[4] = (_Float16)b.x; r[5] = (_Float16)b.y; r[6] = (_Float16)b.z; r[7] = (_Float16)b.w;
    return r;
}
__device__ __forceinline__ f16x8 cvt8p(const float* p) {
    return cvt8(*(const float4*)p, *(const float4*)(p + 4));
}

// LDS-only barrier: waits lgkmcnt(0) but NOT vmcnt (outstanding global stores
// don't serialize the recurrence).
__device__ __forceinline__ void lds_barrier() {
    asm volatile("s_waitcnt lgkmcnt(0)\n\ts_barrier" ::: "memory");
}

// ---------------- sort kernel: counting sort of batches by length -----------
__global__ __launch_bounds__(512) void sort_kernel(
    const int* __restrict__ lengths, int* __restrict__ perm) {
    __shared__ int sbins[512];
    __shared__ int soffs[512];
    const int tid = threadIdx.x;
    sbins[tid] = 0;
    __syncthreads();
    for (int b = tid; b < B_; b += 512) atomicAdd(&sbins[lengths[b] - 1], 1);
    __syncthreads();
    soffs[tid] = sbins[tid];
    __syncthreads();
    for (int d = 1; d < 512; d <<= 1) {
        int v = (tid >= d) ? soffs[tid - d] : 0;
        __syncthreads();
        soffs[tid] += v;
        __syncthreads();
    }
    int excl = soffs[tid] - sbins[tid];   // exclusive prefix
    __syncthreads();
    soffs[tid] = excl;
    __syncthreads();
    for (int b = tid; b < B_; b += 512) {
        const int pos = atomicAdd(&soffs[lengths[b] - 1], 1);
        perm[pos] = b;
    }
}

// ---------------- Kernel A: fused LSTM (measured-best, 445us, VERBATIM) ----
// 256 blocks x 768 threads (12 waves). Block owns 8 length-sorted batch rows.
// Phase 1: wave w computes gate-tiles {2w,2w+1}; A rows 8-15 are ZEROS via
//   exec-masked (col<8) LDS reads + v_mov zeros. x prefetch masked to col<8.
// Phase 3' (after barrier1, overlaps phase2): coop-store h(t-1) LDS->global.
// Phase 2: lane -> (u,b) reads i/f/g/o from sgate, activations, writes fp16 h.
// TIMING RULES (measured):
//  - cvt8(x) MUST consume a load issued >= 1 full step earlier (its load is
//    issued in phase 1 of step t-1, consumed top of phase 1 of step t).
//    Moving the cvt to phase 2 of the SAME step exposed ~1300cyc HBM latency
//    per step: 445 -> 731us. Do not re-order VMEM consumes closer to issues.
//  - Restructures all lose: register-local epilogue 646-751us, 2-slot
//    batch-split pipeline 996us. Keep the 2-phase lockstep.
__global__ __launch_bounds__(768, 1) void lstm_kernel(
    const float* __restrict__ x, const int* __restrict__ lengths,
    const int* __restrict__ perm,
    const float* __restrict__ Wih, const float* __restrict__ Whh,
    const float* __restrict__ bih, const float* __restrict__ bhh,
    _Float16* __restrict__ Hout, float* __restrict__ hT)
{
    __shared__ float sgate[NG_ * GS];       // raw gates [gcol][b]
    __shared__ _Float16 sh[2][8 * HP];      // h double buffer [b][u], 8 real rows
    __shared__ int sgb[BPB], slen[BPB];

    const int tid  = threadIdx.x;
    const int bb   = blockIdx.x * BPB;
    const int wave = tid >> 6;
    const int lane = tid & 63;
    const int col  = lane & 15;
    const int quad = lane >> 4;

    if (tid < BPB) {
        const int g = perm[bb + tid];
        sgb[tid] = g;
        slen[tid] = lengths[g];
    }
    // zero h buffers
    {
        _Float16* shf = &sh[0][0];
        for (int i = tid; i < 2 * 8 * HP; i += 768) shf[i] = (_Float16)0.f;
    }
    __syncthreads();

    int bmax = slen[0];
#pragma unroll
    for (int i = 1; i < BPB; ++i) bmax = max(bmax, slen[i]);

    // ---- MFMA role: 2 gate tiles per wave
    int gc[2]; float bias[2];
    f16x8 wh[2][3], wi[2];
#pragma unroll
    for (int j = 0; j < 2; ++j) {
        const int tau = wave * 2 + j;
        const int g = tau / 6, u6 = tau % 6;
        const int gcj = g * DH_ + u6 * 16 + col;
        gc[j] = gcj;
#pragma unroll
        for (int kf = 0; kf < 3; ++kf)
            wh[j][kf] = cvt8p(Whh + gcj * DH_ + kf * 32 + quad * 8);
        wi[j] = cvt8p(Wih + gcj * DIN_ + quad * 8);
        bias[j] = bih[gcj] + bhh[gcj];
    }

    // ---- epilogue role: one (unit, batch) pair per lane
    const int eu = tid >> 3;          // 0..95
    const int eb = tid & 7;           // 0..7
    float c1 = 0.f, hk1 = 0.f;
    const int len1 = slen[eb];

    // ---- coop-store role
    const bool st_act = tid < 384;
    const int sb = tid / 48;                  // batch row 0..7
    const int su = (tid % 48) * 2;            // unit pair
    _Float16* Hst = Hout + ((long long)sgb[sb] * T_) * DH_ + su;

    // ---- x prefetch, masked to the 8 real A rows
    const bool arow = col < 8;
    const float* xp = x + ((long long)sgb[col & 7] * T_) * DIN_ + quad * 8;
    float4 xc0 = make_float4(0.f, 0.f, 0.f, 0.f), xc1 = xc0;
    if (arow) { xc0 = *(const float4*)xp; xc1 = *(const float4*)(xp + 4); }

    for (int t = 0; t < bmax; ++t) {
        const int buf = t & 1;

        // ---------- phase 1: MFMA (all waves) ----------
        // A rows 8-15 are zeros: masked read, lanes col>=8 keep v_mov zeros.
        f16x8 h0 = 0, h1 = 0, h2 = 0;
        if (arow) {
            const _Float16* hrow = &sh[buf][col * HP];
            h0 = *(const f16x8*)(hrow + 0  + quad * 8);
            h1 = *(const f16x8*)(hrow + 32 + quad * 8);
            h2 = *(const f16x8*)(hrow + 64 + quad * 8);
        }

        // prefetch x(t+1), masked
        const float* xpn = (t + 1 < T_) ? (xp + DIN_) : xp;
        float4 xn0 = make_float4(0.f, 0.f, 0.f, 0.f), xn1 = xn0;
        if (arow) { xn0 = *(const float4*)xpn; xn1 = *(const float4*)(xpn + 4); }

        f16x8 xa = cvt8(xc0, xc1);

#pragma unroll
        for (int j = 0; j < 2; ++j) {
            f32x4 a = {bias[j], bias[j], bias[j], bias[j]};
            a = __builtin_amdgcn_mfma_f32_16x16x32_f16(h0, wh[j][0], a, 0, 0, 0);
            a = __builtin_amdgcn_mfma_f32_16x16x32_f16(h1, wh[j][1], a, 0, 0, 0);
            a = __builtin_amdgcn_mfma_f32_16x16x32_f16(h2, wh[j][2], a, 0, 0, 0);
            a = __builtin_amdgcn_mfma_f32_16x16x32_f16(xa, wi[j],    a, 0, 0, 0);
            if (quad < 2) {  // D rows 0-7 real batch
                float2* sp = (float2*)&sgate[gc[j] * GS + quad * 4];
                sp[0] = float2{a[0], a[1]};
                sp[1] = float2{a[2], a[3]};
            }
        }
        lds_barrier();   // gates visible (also orders prev step's h writes)

        // ---------- phase 3': coop-store h(t-1), overlaps phase 2 ----------
        if (t > 0 && st_act) {
            unsigned v = *(const unsigned*)&sh[buf][sb * HP + su];
            *(unsigned*)Hst = v;
            Hst += DH_;
        }

        // ---------- phase 2: epilogue (one pair per lane) ----------
        {
            float iv = sgate[(0 * DH_ + eu) * GS + eb];
            float fv = sgate[(1 * DH_ + eu) * GS + eb];
            float gv = sgate[(2 * DH_ + eu) * GS + eb];
            float ov = sgate[(3 * DH_ + eu) * GS + eb];
            float cn = sigf(fv) * c1 + sigf(iv) * tanhf_(gv);
            float hn = sigf(ov) * tanhf_(cn);
            const bool m = t < len1;
            c1  = m ? cn : c1;
            hk1 = m ? hn : hk1;
            sh[buf ^ 1][eb * HP + eu] = (_Float16)hk1;
        }
        lds_barrier();   // h(t) visible

        xp = xpn; xc0 = xn0; xc1 = xn1;
    }

    // final H column t = bmax-1
    if (st_act) {
        unsigned v = *(const unsigned*)&sh[bmax & 1][sb * HP + su];
        *(unsigned*)Hst = v;
    }

    hT[sgb[eb] * DH_ + eu] = hk1;
}

// ---------------- Kernel B: fused Q/qk + logits/softmax/ctx + MoE head -----
// One block per batch, 256 threads. Round-5 base (measured ~249us tail) with
// two WITHIN-PHASE memory-parallelism changes (no state live across phases —
// the round-6 cross-phase hoist cost VGPR/occupancy and regressed):
//  - logits: rows t0/t1 interleaved in ONE loop, loads UNCONDITIONAL (always
//    in-bounds; garbage rows masked at the -1e30/exp selects, NaN-safe):
//    2 independent 16B loads in flight per iter instead of 1 under a branch.
//  - ctx: unconditional load, FMA predicated on t<len.
__global__ __launch_bounds__(256) void attn_moe_kernel(
    const _Float16* __restrict__ H, const float* __restrict__ hT,
    const int* __restrict__ lengths,
    const float* __restrict__ Wq, const float* __restrict__ bq,
    const float* __restrict__ Wk, const float* __restrict__ bk,
    const float* __restrict__ Wv, const float* __restrict__ bv,
    const float* __restrict__ Wg, const float* __restrict__ bg,
    const float* __restrict__ We1, const float* __restrict__ be1,
    const float* __restrict__ We2, const float* __restrict__ be2,
    float* __restrict__ yhat_out, float* __restrict__ alpha_out,
    float* __restrict__ gl_out)
{
    __shared__ float salpha[T_];
    __shared__ float shT[DH_];
    __shared__ float sQ[DH_];
    __shared__ float sqk[DH_];
    __shared__ float spart[DH_];
    __shared__ float sfeats[2 * DH_];
    __shared__ float sh1[2][DH_];
    __shared__ float sred[4], ssum[4];
    __shared__ float sgl[E_];
    __shared__ float spi[2];
    __shared__ float souts[2];
    __shared__ float sqb_s;
    __shared__ int stopi[2];

    const int b = blockIdx.x, tid = threadIdx.x;
    const int len = lengths[b];
    const float scale = 0.10206207262f; // 1/sqrt(96)

    // ---- fused qk: Q = Wq@hT + bq; qk = (Wk^T Q)*scale; qb = (Q.bk)*scale
    if (tid < DH_) shT[tid] = hT[b * DH_ + tid];
    __syncthreads();
    if (tid < DH_) {
        float acc = bq[tid];
        const float* wr = Wq + tid * DH_;
        for (int d = 0; d < DH_; d += 4) {
            float4 w4 = *(const float4*)(wr + d);
            acc += w4.x * shT[d] + w4.y * shT[d + 1] + w4.z * shT[d + 2] + w4.w * shT[d + 3];
        }
        sQ[tid] = acc;
    }
    __syncthreads();
    if (tid < DH_) {
        float acc = 0.f;
        for (int j = 0; j < DH_; ++j) acc += Wk[j * DH_ + tid] * sQ[j];
        sqk[tid] = acc * scale;
    }
    if (tid >= 192) {                 // wave 3 computes qb in parallel
        const int ln = tid - 192;
        float p = sQ[ln] * bk[ln];
        if (ln < DH_ - 64) p += sQ[ln + 64] * bk[ln + 64];
        for (int off = 32; off; off >>= 1) p += __shfl_xor(p, off);
        if (ln == 0) sqb_s = p * scale;
    }
    __syncthreads();
    const float qbv = sqb_s;

    // ---- logits: rows t0=tid, t1=tid+256 interleaved, unconditional loads
    const _Float16* hr0 = H + ((long long)b * T_ + tid) * DH_;
    const _Float16* hr1 = hr0 + 256 * DH_;
    float l0 = qbv, l1 = qbv;
#pragma unroll
    for (int u = 0; u < DH_; u += 8) {
        f16x8 h0 = *(const f16x8*)(hr0 + u);
        f16x8 h1 = *(const f16x8*)(hr1 + u);
        float4 qa = *(const float4*)&sqk[u];
        float4 qc = *(const float4*)&sqk[u + 4];
        l0 += (float)h0[0] * qa.x + (float)h0[1] * qa.y
            + (float)h0[2] * qa.z + (float)h0[3] * qa.w
            + (float)h0[4] * qc.x + (float)h0[5] * qc.y
            + (float)h0[6] * qc.z + (float)h0[7] * qc.w;
        l1 += (float)h1[0] * qa.x + (float)h1[1] * qa.y
            + (float)h1[2] * qa.z + (float)h1[3] * qa.w
            + (float)h1[4] * qc.x + (float)h1[5] * qc.y
            + (float)h1[6] * qc.z + (float)h1[7] * qc.w;
    }
    const bool v0 = tid < len, v1 = (tid + 256) < len;

    float m = fmaxf(v0 ? l0 : -1e30f, v1 ? l1 : -1e30f);
    for (int off = 32; off; off >>= 1) m = fmaxf(m, __shfl_xor(m, off));
    if ((tid & 63) == 0) sred[tid >> 6] = m;
    __syncthreads();
    m = fmaxf(fmaxf(sred[0], sred[1]), fmaxf(sred[2], sred[3]));

    float e0 = v0 ? EXP2F((l0 - m) * 1.44269504f) : 0.f;
    float e1 = v1 ? EXP2F((l1 - m) * 1.44269504f) : 0.f;
    float s = e0 + e1;
    for (int off = 32; off; off >>= 1) s += __shfl_xor(s, off);
    if ((tid & 63) == 0) ssum[tid >> 6] = s;
    __syncthreads();
    s = (ssum[0] + ssum[1]) + (ssum[2] + ssum[3]);

    const float rinv = RCPF(s);
    const float a0 = e0 * rinv, a1 = e1 * rinv;
    salpha[tid] = a0;
    salpha[tid + 256] = a1;
    alpha_out[(long long)b * T_ + tid] = a0;
    alpha_out[(long long)b * T_ + tid + 256] = a1;
    __syncthreads();

    // ctx raw: 12 u-blocks x 16 t-lanes, f16x8 loads, shfl-tree reduce over tl
    if (tid < 192) {
        const int ub = tid >> 4, tl = tid & 15;
        float acc[8] = {0.f, 0.f, 0.f, 0.f, 0.f, 0.f, 0.f, 0.f};
        const _Float16* hb = H + ((long long)b * T_) * DH_ + ub * 8;
#pragma unroll 4
        for (int k = 0; k < 32; ++k) {
            const int t = tl + (k << 4);
            f16x8 hv = *(const f16x8*)(hb + t * DH_);   // unconditional load
            const float a = salpha[t];
            if (t < len) {                               // predicated FMA
#pragma unroll
                for (int i = 0; i < 8; ++i) acc[i] += a * (float)hv[i];
            }
        }
#pragma unroll
        for (int i = 0; i < 8; ++i) {
            acc[i] += __shfl_xor(acc[i], 1);
            acc[i] += __shfl_xor(acc[i], 2);
            acc[i] += __shfl_xor(acc[i], 4);
            acc[i] += __shfl_xor(acc[i], 8);
        }
        if (tl == 0) {
#pragma unroll
            for (int i = 0; i < 8; ++i) spart[ub * 8 + i] = acc[i];
        }
    }
    __syncthreads();

    // ctx = Wv @ craw + bv ; feats = [ctx, hT]
    if (tid < DH_) {
        float acc = bv[tid];
        const float* wr = Wv + tid * DH_;
        for (int u = 0; u < DH_; u += 4) {
            float4 w4 = *(const float4*)(wr + u);
            acc += w4.x * spart[u] + w4.y * spart[u + 1] + w4.z * spart[u + 2] + w4.w * spart[u + 3];
        }
        sfeats[tid] = acc;             // ctx
        sfeats[DH_ + tid] = shT[tid];  // hT (already in LDS)
    }
    __syncthreads();

    // gate logits: 6 experts x 32 lanes, 6 f-elems per lane
    if (tid < 192) {
        const int e6 = tid >> 5, cc = tid & 31;
        float p = 0.f;
        const float* wg = Wg + e6 * 2 * DH_;
#pragma unroll
        for (int j = 0; j < 6; ++j) p += wg[cc * 6 + j] * sfeats[cc * 6 + j];
        for (int off = 16; off; off >>= 1) p += __shfl_xor(p, off);
        if (cc == 0) {
            float g = p + bg[e6];
            sgl[e6] = g;
            gl_out[b * E_ + e6] = g;
        }
    }
    __syncthreads();

    if (tid == 0) {
        int i0 = 0; float v0_ = sgl[0];
        for (int ee = 1; ee < E_; ++ee) if (sgl[ee] > v0_) { v0_ = sgl[ee]; i0 = ee; }
        int i1 = -1; float v1_ = -1e30f;
        for (int ee = 0; ee < E_; ++ee) {
            if (ee == i0) continue;
            if (sgl[ee] > v1_) { v1_ = sgl[ee]; i1 = ee; }
        }
        float ex1 = EXP2F((v1_ - v0_) * 1.44269504f);
        float inv = RCPF(1.f + ex1);
        spi[0] = inv; spi[1] = ex1 * inv;
        stopi[0] = i0; stopi[1] = i1;
    }
    __syncthreads();

    // expert hidden for the 2 selected experts
    if (tid < 192) {
        const int e2 = tid / DH_, u = tid - e2 * DH_;
        const int ex = stopi[e2];
        float acc = be1[ex * DH_ + u];
        const float* w = We1 + ((long long)ex * DH_ + u) * (2 * DH_);
        for (int f = 0; f < 2 * DH_; f += 4) {
            float4 w4 = *(const float4*)(w + f);
            acc += w4.x * sfeats[f] + w4.y * sfeats[f + 1] + w4.z * sfeats[f + 2] + w4.w * sfeats[f + 3];
        }
        sh1[e2][u] = fmaxf(acc, 0.f);
    }
    __syncthreads();

    // final expert outputs: one wave per expert
    if (tid < 128) {
        const int e2 = tid >> 6, ln = tid & 63;
        const int ex = stopi[e2];
        const float* w2 = We2 + ex * DH_;
        float p = sh1[e2][ln] * w2[ln];
        if (ln < DH_ - 64) p += sh1[e2][ln + 64] * w2[ln + 64];
        for (int off = 32; off; off >>= 1) p += __shfl_xor(p, off);
        if (ln == 0) souts[e2] = p + be2[ex];
    }
    __syncthreads();
    if (tid == 0)
        yhat_out[b] = spi[0] * souts[0] + spi[1] * souts[1];
}

extern "C" void kernel_launch(void* const* d_in, const int* in_sizes, int n_in,
                              void* d_out, int out_size, void* d_ws, size_t ws_size,
                              hipStream_t stream) {
    const float* x   = (const float*)d_in[0];
    const int* lengths = (const int*)d_in[1];
    // d_in[2] = mask (recomputed from lengths)
    const float* Wih = (const float*)d_in[3];
    const float* Whh = (const float*)d_in[4];
    const float* bih = (const float*)d_in[5];
    const float* bhh = (const float*)d_in[6];
    const float* Wq  = (const float*)d_in[7];
    const float* bq  = (const float*)d_in[8];
    const float* Wk  = (const float*)d_in[9];
    const float* bk  = (const float*)d_in[10];
    const float* Wv  = (const float*)d_in[11];
    const float* bv  = (const float*)d_in[12];
    const float* Wg  = (const float*)d_in[13];
    const float* bg  = (const float*)d_in[14];
    const float* We1 = (const float*)d_in[15];
    const float* be1 = (const float*)d_in[16];
    const float* We2 = (const float*)d_in[17];
    const float* be2 = (const float*)d_in[18];

    float* yhat  = (float*)d_out;
    float* alpha = yhat + B_;
    float* gl    = alpha + (size_t)B_ * T_;

    char* ws = (char*)d_ws;
    _Float16* Hws = (_Float16*)ws;                                   // B*T*96 fp16
    float* hTws = (float*)(ws + (size_t)B_ * T_ * DH_ * 2);          // B*96 f32
    int* perm   = (int*)(hTws + (size_t)B_ * DH_);                   // B

    sort_kernel<<<dim3(1), dim3(512), 0, stream>>>(lengths, perm);

    lstm_kernel<<<dim3(B_ / BPB), dim3(768), 0, stream>>>(
        x, lengths, perm, Wih, Whh, bih, bhh, Hws, hTws);
    attn_moe_kernel<<<dim3(B_), dim3(256), 0, stream>>>(
        Hws, hTws, lengths, Wq, bq, Wk, bk, Wv, bv, Wg, bg,
        We1, be1, We2, be2, yhat, alpha, gl);
}

// Round 10
// 718.643 us; speedup vs baseline: 1.3710x; 1.0422x over previous
//
#include <hip/hip_runtime.h>
#include <hip/hip_bf16.h>

#define B_ 2048
#define T_ 512
#define DIN_ 32
#define DH_ 96
#define NG_ 384
#define E_ 6

#define BPB 8      // batch rows per block
#define HP 104     // fp16 elems per h row (96 + 8 pad, keeps 16B alignment)
#define GS 10      // dwords per sgate row

typedef __attribute__((ext_vector_type(8))) _Float16 f16x8;
typedef __attribute__((ext_vector_type(4))) float f32x4;

#if defined(__has_builtin)
# if __has_builtin(__builtin_amdgcn_exp2f)
#  define EXP2F(x) __builtin_amdgcn_exp2f(x)
# endif
# if __has_builtin(__builtin_amdgcn_rcpf)
#  define RCPF(x) __builtin_amdgcn_rcpf(x)
# endif
#endif
#ifndef EXP2F
# define EXP2F(x) exp2f(x)
#endif
#ifndef RCPF
# define RCPF(x) (1.0f/(x))
#endif

__device__ __forceinline__ float sigf(float x) {
    return RCPF(1.0f + EXP2F(x * -1.44269504f));
}
__device__ __forceinline__ float tanhf_(float x) {
    return 1.0f - 2.0f * RCPF(1.0f + EXP2F(x * 2.88539008f));
}

__device__ __forceinline__ f16x8 cvt8(float4 a, float4 b) {
    f16x8 r;
    r[0] = (_Float16)a.x; r[1] = (_Float16)a.y; r[2] = (_Float16)a.z; r[3] = (_Float16)a.w;
    r[4] = (_Float16)b.x; r[5] = (_Float16)b.y; r[6] = (_Float16)b.z; r[7] = (_Float16)b.w;
    return r;
}
__device__ __forceinline__ f16x8 cvt8p(const float* p) {
    return cvt8(*(const float4*)p, *(const float4*)(p + 4));
}

// LDS-only barrier: waits lgkmcnt(0) but NOT vmcnt (outstanding global stores
// don't serialize the recurrence).
__device__ __forceinline__ void lds_barrier() {
    asm volatile("s_waitcnt lgkmcnt(0)\n\ts_barrier" ::: "memory");
}

// ---------------- sort kernel: counting sort of batches by length -----------
__global__ __launch_bounds__(512) void sort_kernel(
    const int* __restrict__ lengths, int* __restrict__ perm) {
    __shared__ int sbins[512];
    __shared__ int soffs[512];
    const int tid = threadIdx.x;
    sbins[tid] = 0;
    __syncthreads();
    for (int b = tid; b < B_; b += 512) atomicAdd(&sbins[lengths[b] - 1], 1);
    __syncthreads();
    soffs[tid] = sbins[tid];
    __syncthreads();
    for (int d = 1; d < 512; d <<= 1) {
        int v = (tid >= d) ? soffs[tid - d] : 0;
        __syncthreads();
        soffs[tid] += v;
        __syncthreads();
    }
    int excl = soffs[tid] - sbins[tid];   // exclusive prefix
    __syncthreads();
    soffs[tid] = excl;
    __syncthreads();
    for (int b = tid; b < B_; b += 512) {
        const int pos = atomicAdd(&soffs[lengths[b] - 1], 1);
        perm[pos] = b;
    }
}

// ---------------- Kernel A: fused LSTM + attention + MoE --------------------
// 256 blocks x 768 threads. Recurrence part is the measured-best 445us
// structure, VERBATIM. After the recurrence, the SAME block computes
// attention + MoE for its own 8 batches: H rows are L2-hot (just written by
// this block), hT comes from registers via LDS. Early-finishing blocks'
// attn overlaps late blocks' lstm — the separate 250us attn wall collapses
// into lstm idle time. All dependencies are block-local (no cross-block
// ordering assumed; one threadfence_block+barrier makes H stores L2-visible).
// TIMING RULES (measured):
//  - cvt8(x) MUST consume a load issued >= 1 full step earlier. Moving the
//    cvt closer exposed ~1300cyc HBM latency/step: 445 -> 731us.
//  - Restructures of the recurrence all lose: register-local epilogue
//    646-751us, 2-slot pipeline 996us. Keep the 2-phase lockstep.
//  - attn: conditional H loads only (unconditional = +50% traffic, +55us);
//    no cross-phase register hoisting (VGPR cost, +75us).
__global__ __launch_bounds__(768, 1) void lstm_attn_kernel(
    const float* __restrict__ x, const int* __restrict__ lengths,
    const int* __restrict__ perm,
    const float* __restrict__ Wih, const float* __restrict__ Whh,
    const float* __restrict__ bih, const float* __restrict__ bhh,
    const float* __restrict__ Wq, const float* __restrict__ bq,
    const float* __restrict__ Wk, const float* __restrict__ bk,
    const float* __restrict__ Wv, const float* __restrict__ bv,
    const float* __restrict__ Wg, const float* __restrict__ bg,
    const float* __restrict__ We1, const float* __restrict__ be1,
    const float* __restrict__ We2, const float* __restrict__ be2,
    _Float16* __restrict__ Hout,
    float* __restrict__ yhat_out, float* __restrict__ alpha_out,
    float* __restrict__ gl_out)
{
    __shared__ float sgate[NG_ * GS];       // raw gates [gcol][b]
    __shared__ _Float16 sh[2][8 * HP];      // h double buffer [b][u]
    __shared__ int sgb[BPB], slen[BPB];
    // ---- attn-phase LDS (used only after the recurrence)
    __shared__ float slog[BPB][T_];         // logits -> alpha, 16 KB
    __shared__ float shT8[BPB][DH_];
    __shared__ float sQ8[BPB][DH_];
    __shared__ float sqk8[BPB][DH_];
    __shared__ float scraw[BPB][DH_];
    __shared__ float sfeats[BPB][2 * DH_];
    __shared__ float sh1_[BPB][2][DH_];
    __shared__ float sqb[BPB];
    __shared__ float sgl[BPB][E_];
    __shared__ float spi2[BPB][2];
    __shared__ float souts[BPB][2];
    __shared__ int stopi2[BPB][2];

    const int tid  = threadIdx.x;
    const int bb   = blockIdx.x * BPB;
    const int wave = tid >> 6;
    const int lane = tid & 63;
    const int col  = lane & 15;
    const int quad = lane >> 4;

    if (tid < BPB) {
        const int g = perm[bb + tid];
        sgb[tid] = g;
        slen[tid] = lengths[g];
    }
    // zero h buffers
    {
        _Float16* shf = &sh[0][0];
        for (int i = tid; i < 2 * 8 * HP; i += 768) shf[i] = (_Float16)0.f;
    }
    __syncthreads();

    int bmax = slen[0];
#pragma unroll
    for (int i = 1; i < BPB; ++i) bmax = max(bmax, slen[i]);

    // ---- MFMA role: 2 gate tiles per wave
    int gc[2]; float bias[2];
    f16x8 wh[2][3], wi[2];
#pragma unroll
    for (int j = 0; j < 2; ++j) {
        const int tau = wave * 2 + j;
        const int g = tau / 6, u6 = tau % 6;
        const int gcj = g * DH_ + u6 * 16 + col;
        gc[j] = gcj;
#pragma unroll
        for (int kf = 0; kf < 3; ++kf)
            wh[j][kf] = cvt8p(Whh + gcj * DH_ + kf * 32 + quad * 8);
        wi[j] = cvt8p(Wih + gcj * DIN_ + quad * 8);
        bias[j] = bih[gcj] + bhh[gcj];
    }

    // ---- epilogue role: one (unit, batch) pair per lane
    const int eu = tid >> 3;          // 0..95
    const int eb = tid & 7;           // 0..7
    float c1 = 0.f, hk1 = 0.f;
    const int len1 = slen[eb];

    // ---- coop-store role
    const bool st_act = tid < 384;
    const int sb = tid / 48;                  // batch row 0..7
    const int su = (tid % 48) * 2;            // unit pair
    _Float16* Hst = Hout + ((long long)sgb[sb] * T_) * DH_ + su;

    // ---- x prefetch, masked to the 8 real A rows
    const bool arow = col < 8;
    const float* xp = x + ((long long)sgb[col & 7] * T_) * DIN_ + quad * 8;
    float4 xc0 = make_float4(0.f, 0.f, 0.f, 0.f), xc1 = xc0;
    if (arow) { xc0 = *(const float4*)xp; xc1 = *(const float4*)(xp + 4); }

    for (int t = 0; t < bmax; ++t) {
        const int buf = t & 1;

        // ---------- phase 1: MFMA (all waves) ----------
        f16x8 h0 = 0, h1 = 0, h2 = 0;
        if (arow) {
            const _Float16* hrow = &sh[buf][col * HP];
            h0 = *(const f16x8*)(hrow + 0  + quad * 8);
            h1 = *(const f16x8*)(hrow + 32 + quad * 8);
            h2 = *(const f16x8*)(hrow + 64 + quad * 8);
        }

        // prefetch x(t+1), masked
        const float* xpn = (t + 1 < T_) ? (xp + DIN_) : xp;
        float4 xn0 = make_float4(0.f, 0.f, 0.f, 0.f), xn1 = xn0;
        if (arow) { xn0 = *(const float4*)xpn; xn1 = *(const float4*)(xpn + 4); }

        f16x8 xa = cvt8(xc0, xc1);

#pragma unroll
        for (int j = 0; j < 2; ++j) {
            f32x4 a = {bias[j], bias[j], bias[j], bias[j]};
            a = __builtin_amdgcn_mfma_f32_16x16x32_f16(h0, wh[j][0], a, 0, 0, 0);
            a = __builtin_amdgcn_mfma_f32_16x16x32_f16(h1, wh[j][1], a, 0, 0, 0);
            a = __builtin_amdgcn_mfma_f32_16x16x32_f16(h2, wh[j][2], a, 0, 0, 0);
            a = __builtin_amdgcn_mfma_f32_16x16x32_f16(xa, wi[j],    a, 0, 0, 0);
            if (quad < 2) {
                float2* sp = (float2*)&sgate[gc[j] * GS + quad * 4];
                sp[0] = float2{a[0], a[1]};
                sp[1] = float2{a[2], a[3]};
            }
        }
        lds_barrier();   // gates visible (also orders prev step's h writes)

        // ---------- phase 3': coop-store h(t-1), overlaps phase 2 ----------
        if (t > 0 && st_act) {
            unsigned v = *(const unsigned*)&sh[buf][sb * HP + su];
            *(unsigned*)Hst = v;
            Hst += DH_;
        }

        // ---------- phase 2: epilogue (one pair per lane) ----------
        {
            float iv = sgate[(0 * DH_ + eu) * GS + eb];
            float fv = sgate[(1 * DH_ + eu) * GS + eb];
            float gv = sgate[(2 * DH_ + eu) * GS + eb];
            float ov = sgate[(3 * DH_ + eu) * GS + eb];
            float cn = sigf(fv) * c1 + sigf(iv) * tanhf_(gv);
            float hn = sigf(ov) * tanhf_(cn);
            const bool m = t < len1;
            c1  = m ? cn : c1;
            hk1 = m ? hn : hk1;
            sh[buf ^ 1][eb * HP + eu] = (_Float16)hk1;
        }
        lds_barrier();   // h(t) visible

        xp = xpn; xc0 = xn0; xc1 = xn1;
    }

    // final H column t = bmax-1
    if (st_act) {
        unsigned v = *(const unsigned*)&sh[bmax & 1][sb * HP + su];
        *(unsigned*)Hst = v;
    }

    // ================== fused attention + MoE (block-local) ==================
    shT8[eb][eu] = hk1;           // hT into LDS from registers
    __threadfence_block();        // drain this block's H stores to L2
    __syncthreads();              // H + shT8 visible to all threads

    const int abi = tid / 96;           // attn batch 0..7
    const int au  = tid - abi * 96;     // unit 0..95
    const int ag  = sgb[abi];
    const int alen = slen[abi];
    const float scale = 0.10206207262f; // 1/sqrt(96)

    // ---- Q = Wq @ hT + bq  (all 768 threads: 8 batches x 96 units)
    {
        float acc = bq[au];
        const float* wr = Wq + au * DH_;
        const float* ht = &shT8[abi][0];
        for (int d = 0; d < DH_; d += 4) {
            float4 w4 = *(const float4*)(wr + d);
            acc += w4.x * ht[d] + w4.y * ht[d + 1] + w4.z * ht[d + 2] + w4.w * ht[d + 3];
        }
        sQ8[abi][au] = acc;
    }
    __syncthreads();

    // ---- qk = (Wk^T Q)*scale (all threads); qb via waves 0-7
    {
        float acc = 0.f;
        const float* qv = &sQ8[abi][0];
        for (int j = 0; j < DH_; ++j) acc += Wk[j * DH_ + au] * qv[j];
        sqk8[abi][au] = acc * scale;
    }
    if (wave < 8) {
        float p = sQ8[wave][lane] * bk[lane];
        if (lane < 32) p += sQ8[wave][64 + lane] * bk[64 + lane];
        for (int off = 32; off; off >>= 1) p += __shfl_xor(p, off);
        if (lane == 0) sqb[wave] = p * scale;
    }
    __syncthreads();

    // ---- logits for all 8*512 rows (conditional loads: t<len only)
    for (int k = 0; k < 6; ++k) {
        const int r = tid + k * 768;
        if (r < BPB * T_) {
            const int bi2 = r >> 9, t = r & (T_ - 1);
            float l = -1e30f;
            if (t < slen[bi2]) {
                const _Float16* hr = Hout + ((long long)sgb[bi2] * T_ + t) * DH_;
                const float* qk = &sqk8[bi2][0];
                float acc = sqb[bi2];
#pragma unroll
                for (int u = 0; u < DH_; u += 8) {
                    f16x8 hv = *(const f16x8*)(hr + u);
                    float4 qa = *(const float4*)(qk + u);
                    float4 qc = *(const float4*)(qk + u + 4);
                    acc += (float)hv[0] * qa.x + (float)hv[1] * qa.y
                         + (float)hv[2] * qa.z + (float)hv[3] * qa.w
                         + (float)hv[4] * qc.x + (float)hv[5] * qc.y
                         + (float)hv[6] * qc.z + (float)hv[7] * qc.w;
                }
                l = acc;
            }
            slog[0][r] = l;    // flat write (slog is [8][512] contiguous)
        }
    }
    __syncthreads();

    // ---- per-batch softmax: wave w handles batch w (8 rows per lane)
    if (wave < 8) {
        float lv[8];
#pragma unroll
        for (int j = 0; j < 8; ++j) lv[j] = slog[wave][lane + 64 * j];
        float m = lv[0];
#pragma unroll
        for (int j = 1; j < 8; ++j) m = fmaxf(m, lv[j]);
        for (int off = 32; off; off >>= 1) m = fmaxf(m, __shfl_xor(m, off));
        float ev[8]; float s = 0.f;
#pragma unroll
        for (int j = 0; j < 8; ++j) { ev[j] = EXP2F((lv[j] - m) * 1.44269504f); s += ev[j]; }
        for (int off = 32; off; off >>= 1) s += __shfl_xor(s, off);
        const float rinv = RCPF(s);
        float* aout = alpha_out + (long long)sgb[wave] * T_;
#pragma unroll
        for (int j = 0; j < 8; ++j) {
            const float a = ev[j] * rinv;   // invalid rows: ev=0 -> a=0
            slog[wave][lane + 64 * j] = a;
            aout[lane + 64 * j] = a;
        }
    }
    __syncthreads();

    // ---- ctx raw: thread = (abi, chunk ub, t-lane tl); f16x8 loads
    {
        const int ub = au >> 3, tl = au & 7;
        float acc[8] = {0.f, 0.f, 0.f, 0.f, 0.f, 0.f, 0.f, 0.f};
        const _Float16* hb = Hout + ((long long)ag * T_) * DH_ + ub * 8;
        for (int k = 0; k < 64; ++k) {
            const int t = tl + (k << 3);
            if (t < alen) {
                f16x8 hv = *(const f16x8*)(hb + t * DH_);
                const float a = slog[abi][t];
#pragma unroll
                for (int i = 0; i < 8; ++i) acc[i] += a * (float)hv[i];
            }
        }
#pragma unroll
        for (int i = 0; i < 8; ++i) {
            acc[i] += __shfl_xor(acc[i], 1);
            acc[i] += __shfl_xor(acc[i], 2);
            acc[i] += __shfl_xor(acc[i], 4);
        }
        if (tl == 0) {
#pragma unroll
            for (int i = 0; i < 8; ++i) scraw[abi][ub * 8 + i] = acc[i];
        }
    }
    __syncthreads();

    // ---- ctx = Wv @ craw + bv ; feats = [ctx, hT]
    {
        float acc = bv[au];
        const float* wr = Wv + au * DH_;
        const float* cr = &scraw[abi][0];
        for (int u2 = 0; u2 < DH_; u2 += 4) {
            float4 w4 = *(const float4*)(wr + u2);
            acc += w4.x * cr[u2] + w4.y * cr[u2 + 1] + w4.z * cr[u2 + 2] + w4.w * cr[u2 + 3];
        }
        sfeats[abi][au] = acc;
        sfeats[abi][DH_ + au] = shT8[abi][au];
    }
    __syncthreads();

    // ---- gate logits: thread = (abi, expert ge, 16-lane gc_), 12 elems each
    {
        const int ge = au >> 4, gcc = au & 15;
        float p = 0.f;
        const float* wg = Wg + ge * 2 * DH_ + gcc * 12;
        const float* ft = &sfeats[abi][gcc * 12];
#pragma unroll
        for (int j = 0; j < 12; ++j) p += wg[j] * ft[j];
        p += __shfl_xor(p, 1); p += __shfl_xor(p, 2);
        p += __shfl_xor(p, 4); p += __shfl_xor(p, 8);
        if (gcc == 0) {
            const float g2 = p + bg[ge];
            sgl[abi][ge] = g2;
            gl_out[ag * E_ + ge] = g2;
        }
    }
    __syncthreads();

    // ---- top-2 + pi per batch
    if (tid < BPB) {
        int i0 = 0; float v0 = sgl[tid][0];
        for (int ee = 1; ee < E_; ++ee) if (sgl[tid][ee] > v0) { v0 = sgl[tid][ee]; i0 = ee; }
        int i1 = -1; float v1 = -1e30f;
        for (int ee = 0; ee < E_; ++ee) {
            if (ee == i0) continue;
            if (sgl[tid][ee] > v1) { v1 = sgl[tid][ee]; i1 = ee; }
        }
        const float ex1 = EXP2F((v1 - v0) * 1.44269504f);
        const float inv = RCPF(1.f + ex1);
        spi2[tid][0] = inv; spi2[tid][1] = ex1 * inv;
        stopi2[tid][0] = i0; stopi2[tid][1] = i1;
    }
    __syncthreads();

    // ---- expert hidden, 2 passes (8 batches x 96 units each)
#pragma unroll
    for (int e2 = 0; e2 < 2; ++e2) {
        const int ex = stopi2[abi][e2];
        float acc = be1[ex * DH_ + au];
        const float* w = We1 + ((long long)ex * DH_ + au) * (2 * DH_);
        const float* ft = &sfeats[abi][0];
        for (int f = 0; f < 2 * DH_; f += 4) {
            float4 w4 = *(const float4*)(w + f);
            acc += w4.x * ft[f] + w4.y * ft[f + 1] + w4.z * ft[f + 2] + w4.w * ft[f + 3];
        }
        sh1_[abi][e2][au] = fmaxf(acc, 0.f);
    }
    __syncthreads();

    // ---- expert outputs: wave w = batch w; half-wave per expert
    if (wave < 8) {
        const int e2 = lane >> 5, lu = lane & 31;
        const int ex = stopi2[wave][e2];
        const float* w2 = We2 + ex * DH_;
        const float* h1p = &sh1_[wave][e2][0];
        float p = h1p[lu] * w2[lu] + h1p[lu + 32] * w2[lu + 32] + h1p[lu + 64] * w2[lu + 64];
        p += __shfl_xor(p, 1); p += __shfl_xor(p, 2); p += __shfl_xor(p, 4);
        p += __shfl_xor(p, 8); p += __shfl_xor(p, 16);
        if (lu == 0) souts[wave][e2] = p + be2[ex];
    }
    __syncthreads();
    if (tid < BPB)
        yhat_out[sgb[tid]] = spi2[tid][0] * souts[tid][0] + spi2[tid][1] * souts[tid][1];
}

extern "C" void kernel_launch(void* const* d_in, const int* in_sizes, int n_in,
                              void* d_out, int out_size, void* d_ws, size_t ws_size,
                              hipStream_t stream) {
    const float* x   = (const float*)d_in[0];
    const int* lengths = (const int*)d_in[1];
    // d_in[2] = mask (recomputed from lengths)
    const float* Wih = (const float*)d_in[3];
    const float* Whh = (const float*)d_in[4];
    const float* bih = (const float*)d_in[5];
    const float* bhh = (const float*)d_in[6];
    const float* Wq  = (const float*)d_in[7];
    const float* bq  = (const float*)d_in[8];
    const float* Wk  = (const float*)d_in[9];
    const float* bk  = (const float*)d_in[10];
    const float* Wv  = (const float*)d_in[11];
    const float* bv  = (const float*)d_in[12];
    const float* Wg  = (const float*)d_in[13];
    const float* bg  = (const float*)d_in[14];
    const float* We1 = (const float*)d_in[15];
    const float* be1 = (const float*)d_in[16];
    const float* We2 = (const float*)d_in[17];
    const float* be2 = (const float*)d_in[18];

    float* yhat  = (float*)d_out;
    float* alpha = yhat + B_;
    float* gl    = alpha + (size_t)B_ * T_;

    char* ws = (char*)d_ws;
    _Float16* Hws = (_Float16*)ws;                                   // B*T*96 fp16
    int* perm   = (int*)(ws + (size_t)B_ * T_ * DH_ * 2);            // B

    sort_kernel<<<dim3(1), dim3(512), 0, stream>>>(lengths, perm);

    lstm_attn_kernel<<<dim3(B_ / BPB), dim3(768), 0, stream>>>(
        x, lengths, perm, Wih, Whh, bih, bhh,
        Wq, bq, Wk, bk, Wv, bv, Wg, bg, We1, be1, We2, be2,
        Hws, yhat, alpha, gl);
}

// Round 11
// 668.992 us; speedup vs baseline: 1.4728x; 1.0742x over previous
//
#include <hip/hip_runtime.h>
#include <hip/hip_bf16.h>

#define B_ 2048
#define T_ 512
#define DIN_ 32
#define DH_ 96
#define NG_ 384
#define E_ 6

#define BPB 8      // batch rows per block
#define HP 104     // fp16 elems per h row (96 + 8 pad, keeps 16B alignment)
#define GS 10      // dwords per sgate row
#define ATH 384    // groups with bmax<=ATH do attn in the fused tail (hidden
                   // under the lstm wall); longer groups deferred to kernel 2

typedef __attribute__((ext_vector_type(8))) _Float16 f16x8;
typedef __attribute__((ext_vector_type(4))) float f32x4;

#if defined(__has_builtin)
# if __has_builtin(__builtin_amdgcn_exp2f)
#  define EXP2F(x) __builtin_amdgcn_exp2f(x)
# endif
# if __has_builtin(__builtin_amdgcn_rcpf)
#  define RCPF(x) __builtin_amdgcn_rcpf(x)
# endif
#endif
#ifndef EXP2F
# define EXP2F(x) exp2f(x)
#endif
#ifndef RCPF
# define RCPF(x) (1.0f/(x))
#endif

__device__ __forceinline__ float sigf(float x) {
    return RCPF(1.0f + EXP2F(x * -1.44269504f));
}
__device__ __forceinline__ float tanhf_(float x) {
    return 1.0f - 2.0f * RCPF(1.0f + EXP2F(x * 2.88539008f));
}

__device__ __forceinline__ f16x8 cvt8(float4 a, float4 b) {
    f16x8 r;
    r[0] = (_Float16)a.x; r[1] = (_Float16)a.y; r[2] = (_Float16)a.z; r[3] = (_Float16)a.w;
    r[4] = (_Float16)b.x; r[5] = (_Float16)b.y; r[6] = (_Float16)b.z; r[7] = (_Float16)b.w;
    return r;
}
__device__ __forceinline__ f16x8 cvt8p(const float* p) {
    return cvt8(*(const float4*)p, *(const float4*)(p + 4));
}

// LDS-only barrier: waits lgkmcnt(0) but NOT vmcnt (outstanding global stores
// don't serialize the recurrence).
__device__ __forceinline__ void lds_barrier() {
    asm volatile("s_waitcnt lgkmcnt(0)\n\ts_barrier" ::: "memory");
}

// ---------------- sort kernel: counting sort of batches by length -----------
__global__ __launch_bounds__(512) void sort_kernel(
    const int* __restrict__ lengths, int* __restrict__ perm) {
    __shared__ int sbins[512];
    __shared__ int soffs[512];
    const int tid = threadIdx.x;
    sbins[tid] = 0;
    __syncthreads();
    for (int b = tid; b < B_; b += 512) atomicAdd(&sbins[lengths[b] - 1], 1);
    __syncthreads();
    soffs[tid] = sbins[tid];
    __syncthreads();
    for (int d = 1; d < 512; d <<= 1) {
        int v = (tid >= d) ? soffs[tid - d] : 0;
        __syncthreads();
        soffs[tid] += v;
        __syncthreads();
    }
    int excl = soffs[tid] - sbins[tid];   // exclusive prefix
    __syncthreads();
    soffs[tid] = excl;
    __syncthreads();
    for (int b = tid; b < B_; b += 512) {
        const int pos = atomicAdd(&soffs[lengths[b] - 1], 1);
        perm[pos] = b;
    }
}

// ---------------- Kernel A: fused LSTM + (conditional) attention tail -------
// 256 blocks x 768 threads. Recurrence = measured-best 445us structure,
// VERBATIM. After the recurrence: hT stored globally for all groups; then IF
// bmax <= ATH the block computes attn+MoE for its own 8 batches (H L2/LDS
// hot, work hidden under later blocks' lstm). Groups with bmax > ATH are
// handled by attn_moe_kernel at full-GPU parallelism (the wall block's own
// 115us single-CU tail was the round-10 regression).
// TIMING RULES (measured):
//  - cvt8(x) MUST consume a load issued >= 1 full step earlier (445->731us).
//  - Recurrence restructures all lose (646/751/996us). Keep 2-phase lockstep.
//  - attn: conditional H loads only; no cross-phase register hoisting.
__global__ __launch_bounds__(768, 1) void lstm_attn_kernel(
    const float* __restrict__ x, const int* __restrict__ lengths,
    const int* __restrict__ perm,
    const float* __restrict__ Wih, const float* __restrict__ Whh,
    const float* __restrict__ bih, const float* __restrict__ bhh,
    const float* __restrict__ Wq, const float* __restrict__ bq,
    const float* __restrict__ Wk, const float* __restrict__ bk,
    const float* __restrict__ Wv, const float* __restrict__ bv,
    const float* __restrict__ Wg, const float* __restrict__ bg,
    const float* __restrict__ We1, const float* __restrict__ be1,
    const float* __restrict__ We2, const float* __restrict__ be2,
    _Float16* __restrict__ Hout, float* __restrict__ hT,
    float* __restrict__ yhat_out, float* __restrict__ alpha_out,
    float* __restrict__ gl_out)
{
    __shared__ float sgate[NG_ * GS];       // raw gates [gcol][b]
    __shared__ _Float16 sh[2][8 * HP];      // h double buffer [b][u]
    __shared__ int sgb[BPB], slen[BPB];
    // ---- attn-phase LDS (used only in the conditional tail)
    __shared__ float slog[BPB][T_];         // logits -> alpha, 16 KB
    __shared__ float shT8[BPB][DH_];
    __shared__ float sQ8[BPB][DH_];
    __shared__ float sqk8[BPB][DH_];
    __shared__ float scraw[BPB][DH_];
    __shared__ float sfeats[BPB][2 * DH_];
    __shared__ float sh1_[BPB][2][DH_];
    __shared__ float sqb[BPB];
    __shared__ float sgl[BPB][E_];
    __shared__ float spi2[BPB][2];
    __shared__ float souts[BPB][2];
    __shared__ int stopi2[BPB][2];

    const int tid  = threadIdx.x;
    const int bb   = blockIdx.x * BPB;
    const int wave = tid >> 6;
    const int lane = tid & 63;
    const int col  = lane & 15;
    const int quad = lane >> 4;

    if (tid < BPB) {
        const int g = perm[bb + tid];
        sgb[tid] = g;
        slen[tid] = lengths[g];
    }
    // zero h buffers
    {
        _Float16* shf = &sh[0][0];
        for (int i = tid; i < 2 * 8 * HP; i += 768) shf[i] = (_Float16)0.f;
    }
    __syncthreads();

    int bmax = slen[0];
#pragma unroll
    for (int i = 1; i < BPB; ++i) bmax = max(bmax, slen[i]);

    // ---- MFMA role: 2 gate tiles per wave
    int gc[2]; float bias[2];
    f16x8 wh[2][3], wi[2];
#pragma unroll
    for (int j = 0; j < 2; ++j) {
        const int tau = wave * 2 + j;
        const int g = tau / 6, u6 = tau % 6;
        const int gcj = g * DH_ + u6 * 16 + col;
        gc[j] = gcj;
#pragma unroll
        for (int kf = 0; kf < 3; ++kf)
            wh[j][kf] = cvt8p(Whh + gcj * DH_ + kf * 32 + quad * 8);
        wi[j] = cvt8p(Wih + gcj * DIN_ + quad * 8);
        bias[j] = bih[gcj] + bhh[gcj];
    }

    // ---- epilogue role: one (unit, batch) pair per lane
    const int eu = tid >> 3;          // 0..95
    const int eb = tid & 7;           // 0..7
    float c1 = 0.f, hk1 = 0.f;
    const int len1 = slen[eb];

    // ---- coop-store role
    const bool st_act = tid < 384;
    const int sb = tid / 48;                  // batch row 0..7
    const int su = (tid % 48) * 2;            // unit pair
    _Float16* Hst = Hout + ((long long)sgb[sb] * T_) * DH_ + su;

    // ---- x prefetch, masked to the 8 real A rows
    const bool arow = col < 8;
    const float* xp = x + ((long long)sgb[col & 7] * T_) * DIN_ + quad * 8;
    float4 xc0 = make_float4(0.f, 0.f, 0.f, 0.f), xc1 = xc0;
    if (arow) { xc0 = *(const float4*)xp; xc1 = *(const float4*)(xp + 4); }

    for (int t = 0; t < bmax; ++t) {
        const int buf = t & 1;

        // ---------- phase 1: MFMA (all waves) ----------
        f16x8 h0 = 0, h1 = 0, h2 = 0;
        if (arow) {
            const _Float16* hrow = &sh[buf][col * HP];
            h0 = *(const f16x8*)(hrow + 0  + quad * 8);
            h1 = *(const f16x8*)(hrow + 32 + quad * 8);
            h2 = *(const f16x8*)(hrow + 64 + quad * 8);
        }

        // prefetch x(t+1), masked
        const float* xpn = (t + 1 < T_) ? (xp + DIN_) : xp;
        float4 xn0 = make_float4(0.f, 0.f, 0.f, 0.f), xn1 = xn0;
        if (arow) { xn0 = *(const float4*)xpn; xn1 = *(const float4*)(xpn + 4); }

        f16x8 xa = cvt8(xc0, xc1);

#pragma unroll
        for (int j = 0; j < 2; ++j) {
            f32x4 a = {bias[j], bias[j], bias[j], bias[j]};
            a = __builtin_amdgcn_mfma_f32_16x16x32_f16(h0, wh[j][0], a, 0, 0, 0);
            a = __builtin_amdgcn_mfma_f32_16x16x32_f16(h1, wh[j][1], a, 0, 0, 0);
            a = __builtin_amdgcn_mfma_f32_16x16x32_f16(h2, wh[j][2], a, 0, 0, 0);
            a = __builtin_amdgcn_mfma_f32_16x16x32_f16(xa, wi[j],    a, 0, 0, 0);
            if (quad < 2) {
                float2* sp = (float2*)&sgate[gc[j] * GS + quad * 4];
                sp[0] = float2{a[0], a[1]};
                sp[1] = float2{a[2], a[3]};
            }
        }
        lds_barrier();   // gates visible (also orders prev step's h writes)

        // ---------- phase 3': coop-store h(t-1), overlaps phase 2 ----------
        if (t > 0 && st_act) {
            unsigned v = *(const unsigned*)&sh[buf][sb * HP + su];
            *(unsigned*)Hst = v;
            Hst += DH_;
        }

        // ---------- phase 2: epilogue (one pair per lane) ----------
        {
            float iv = sgate[(0 * DH_ + eu) * GS + eb];
            float fv = sgate[(1 * DH_ + eu) * GS + eb];
            float gv = sgate[(2 * DH_ + eu) * GS + eb];
            float ov = sgate[(3 * DH_ + eu) * GS + eb];
            float cn = sigf(fv) * c1 + sigf(iv) * tanhf_(gv);
            float hn = sigf(ov) * tanhf_(cn);
            const bool m = t < len1;
            c1  = m ? cn : c1;
            hk1 = m ? hn : hk1;
            sh[buf ^ 1][eb * HP + eu] = (_Float16)hk1;
        }
        lds_barrier();   // h(t) visible

        xp = xpn; xc0 = xn0; xc1 = xn1;
    }

    // final H column t = bmax-1
    if (st_act) {
        unsigned v = *(const unsigned*)&sh[bmax & 1][sb * HP + su];
        *(unsigned*)Hst = v;
    }

    // hT to global for ALL groups (kernel 2 needs it for deferred groups)
    hT[sgb[eb] * DH_ + eu] = hk1;

    if (bmax > ATH) return;   // long groups: attn at full-GPU parallelism in kernel 2

    // ============ fused attention + MoE (block-local, hidden groups) ========
    shT8[eb][eu] = hk1;           // hT into LDS from registers
    __threadfence_block();        // drain this block's H stores
    __syncthreads();              // H + shT8 visible to all threads

    const int abi = tid / 96;           // attn batch 0..7
    const int au  = tid - abi * 96;     // unit 0..95
    const int ag  = sgb[abi];
    const int alen = slen[abi];
    const float scale = 0.10206207262f; // 1/sqrt(96)

    // ---- Q = Wq @ hT + bq  (all 768 threads: 8 batches x 96 units)
    {
        float acc = bq[au];
        const float* wr = Wq + au * DH_;
        const float* ht = &shT8[abi][0];
        for (int d = 0; d < DH_; d += 4) {
            float4 w4 = *(const float4*)(wr + d);
            acc += w4.x * ht[d] + w4.y * ht[d + 1] + w4.z * ht[d + 2] + w4.w * ht[d + 3];
        }
        sQ8[abi][au] = acc;
    }
    __syncthreads();

    // ---- qk = (Wk^T Q)*scale (all threads); qb via waves 0-7
    {
        float acc = 0.f;
        const float* qv = &sQ8[abi][0];
        for (int j = 0; j < DH_; ++j) acc += Wk[j * DH_ + au] * qv[j];
        sqk8[abi][au] = acc * scale;
    }
    if (wave < 8) {
        float p = sQ8[wave][lane] * bk[lane];
        if (lane < 32) p += sQ8[wave][64 + lane] * bk[64 + lane];
        for (int off = 32; off; off >>= 1) p += __shfl_xor(p, off);
        if (lane == 0) sqb[wave] = p * scale;
    }
    __syncthreads();

    // ---- logits for all 8*512 rows (conditional loads: t<len only)
    for (int k = 0; k < 6; ++k) {
        const int r = tid + k * 768;
        if (r < BPB * T_) {
            const int bi2 = r >> 9, t = r & (T_ - 1);
            float l = -1e30f;
            if (t < slen[bi2]) {
                const _Float16* hr = Hout + ((long long)sgb[bi2] * T_ + t) * DH_;
                const float* qk = &sqk8[bi2][0];
                float acc = sqb[bi2];
#pragma unroll
                for (int u = 0; u < DH_; u += 8) {
                    f16x8 hv = *(const f16x8*)(hr + u);
                    float4 qa = *(const float4*)(qk + u);
                    float4 qc = *(const float4*)(qk + u + 4);
                    acc += (float)hv[0] * qa.x + (float)hv[1] * qa.y
                         + (float)hv[2] * qa.z + (float)hv[3] * qa.w
                         + (float)hv[4] * qc.x + (float)hv[5] * qc.y
                         + (float)hv[6] * qc.z + (float)hv[7] * qc.w;
                }
                l = acc;
            }
            slog[0][r] = l;    // flat write (slog is [8][512] contiguous)
        }
    }
    __syncthreads();

    // ---- per-batch softmax: wave w handles batch w (8 rows per lane)
    if (wave < 8) {
        float lv[8];
#pragma unroll
        for (int j = 0; j < 8; ++j) lv[j] = slog[wave][lane + 64 * j];
        float m = lv[0];
#pragma unroll
        for (int j = 1; j < 8; ++j) m = fmaxf(m, lv[j]);
        for (int off = 32; off; off >>= 1) m = fmaxf(m, __shfl_xor(m, off));
        float ev[8]; float s = 0.f;
#pragma unroll
        for (int j = 0; j < 8; ++j) { ev[j] = EXP2F((lv[j] - m) * 1.44269504f); s += ev[j]; }
        for (int off = 32; off; off >>= 1) s += __shfl_xor(s, off);
        const float rinv = RCPF(s);
        float* aout = alpha_out + (long long)sgb[wave] * T_;
#pragma unroll
        for (int j = 0; j < 8; ++j) {
            const float a = ev[j] * rinv;   // invalid rows: ev=0 -> a=0
            slog[wave][lane + 64 * j] = a;
            aout[lane + 64 * j] = a;
        }
    }
    __syncthreads();

    // ---- ctx raw: thread = (abi, chunk ub, t-lane tl); f16x8 loads
    {
        const int ub = au >> 3, tl = au & 7;
        float acc[8] = {0.f, 0.f, 0.f, 0.f, 0.f, 0.f, 0.f, 0.f};
        const _Float16* hb = Hout + ((long long)ag * T_) * DH_ + ub * 8;
        for (int k = 0; k < 64; ++k) {
            const int t = tl + (k << 3);
            if (t < alen) {
                f16x8 hv = *(const f16x8*)(hb + t * DH_);
                const float a = slog[abi][t];
#pragma unroll
                for (int i = 0; i < 8; ++i) acc[i] += a * (float)hv[i];
            }
        }
#pragma unroll
        for (int i = 0; i < 8; ++i) {
            acc[i] += __shfl_xor(acc[i], 1);
            acc[i] += __shfl_xor(acc[i], 2);
            acc[i] += __shfl_xor(acc[i], 4);
        }
        if (tl == 0) {
#pragma unroll
            for (int i = 0; i < 8; ++i) scraw[abi][ub * 8 + i] = acc[i];
        }
    }
    __syncthreads();

    // ---- ctx = Wv @ craw + bv ; feats = [ctx, hT]
    {
        float acc = bv[au];
        const float* wr = Wv + au * DH_;
        const float* cr = &scraw[abi][0];
        for (int u2 = 0; u2 < DH_; u2 += 4) {
            float4 w4 = *(const float4*)(wr + u2);
            acc += w4.x * cr[u2] + w4.y * cr[u2 + 1] + w4.z * cr[u2 + 2] + w4.w * cr[u2 + 3];
        }
        sfeats[abi][au] = acc;
        sfeats[abi][DH_ + au] = shT8[abi][au];
    }
    __syncthreads();

    // ---- gate logits: thread = (abi, expert ge, 16-lane gcc), 12 elems each
    {
        const int ge = au >> 4, gcc = au & 15;
        float p = 0.f;
        const float* wg = Wg + ge * 2 * DH_ + gcc * 12;
        const float* ft = &sfeats[abi][gcc * 12];
#pragma unroll
        for (int j = 0; j < 12; ++j) p += wg[j] * ft[j];
        p += __shfl_xor(p, 1); p += __shfl_xor(p, 2);
        p += __shfl_xor(p, 4); p += __shfl_xor(p, 8);
        if (gcc == 0) {
            const float g2 = p + bg[ge];
            sgl[abi][ge] = g2;
            gl_out[ag * E_ + ge] = g2;
        }
    }
    __syncthreads();

    // ---- top-2 + pi per batch
    if (tid < BPB) {
        int i0 = 0; float v0 = sgl[tid][0];
        for (int ee = 1; ee < E_; ++ee) if (sgl[tid][ee] > v0) { v0 = sgl[tid][ee]; i0 = ee; }
        int i1 = -1; float v1 = -1e30f;
        for (int ee = 0; ee < E_; ++ee) {
            if (ee == i0) continue;
            if (sgl[tid][ee] > v1) { v1 = sgl[tid][ee]; i1 = ee; }
        }
        const float ex1 = EXP2F((v1 - v0) * 1.44269504f);
        const float inv = RCPF(1.f + ex1);
        spi2[tid][0] = inv; spi2[tid][1] = ex1 * inv;
        stopi2[tid][0] = i0; stopi2[tid][1] = i1;
    }
    __syncthreads();

    // ---- expert hidden, 2 passes (8 batches x 96 units each)
#pragma unroll
    for (int e2 = 0; e2 < 2; ++e2) {
        const int ex = stopi2[abi][e2];
        float acc = be1[ex * DH_ + au];
        const float* w = We1 + ((long long)ex * DH_ + au) * (2 * DH_);
        const float* ft = &sfeats[abi][0];
        for (int f = 0; f < 2 * DH_; f += 4) {
            float4 w4 = *(const float4*)(w + f);
            acc += w4.x * ft[f] + w4.y * ft[f + 1] + w4.z * ft[f + 2] + w4.w * ft[f + 3];
        }
        sh1_[abi][e2][au] = fmaxf(acc, 0.f);
    }
    __syncthreads();

    // ---- expert outputs: wave w = batch w; half-wave per expert
    if (wave < 8) {
        const int e2 = lane >> 5, lu = lane & 31;
        const int ex = stopi2[wave][e2];
        const float* w2 = We2 + ex * DH_;
        const float* h1p = &sh1_[wave][e2][0];
        float p = h1p[lu] * w2[lu] + h1p[lu + 32] * w2[lu + 32] + h1p[lu + 64] * w2[lu + 64];
        p += __shfl_xor(p, 1); p += __shfl_xor(p, 2); p += __shfl_xor(p, 4);
        p += __shfl_xor(p, 8); p += __shfl_xor(p, 16);
        if (lu == 0) souts[wave][e2] = p + be2[ex];
    }
    __syncthreads();
    if (tid < BPB)
        yhat_out[sgb[tid]] = spi2[tid][0] * souts[tid][0] + spi2[tid][1] * souts[tid][1];
}

// ---------------- Kernel B: attn+MoE for DEFERRED groups (bmax > ATH) ------
// Round-5 proven per-batch structure (256 thr), indexed through perm; blocks
// whose group was handled in the fused tail exit immediately. Stream ordering
// guarantees H/hT visibility (kernel boundary).
__global__ __launch_bounds__(256) void attn_moe_kernel(
    const _Float16* __restrict__ H, const float* __restrict__ hT,
    const int* __restrict__ lengths, const int* __restrict__ perm,
    const float* __restrict__ Wq, const float* __restrict__ bq,
    const float* __restrict__ Wk, const float* __restrict__ bk,
    const float* __restrict__ Wv, const float* __restrict__ bv,
    const float* __restrict__ Wg, const float* __restrict__ bg,
    const float* __restrict__ We1, const float* __restrict__ be1,
    const float* __restrict__ We2, const float* __restrict__ be2,
    float* __restrict__ yhat_out, float* __restrict__ alpha_out,
    float* __restrict__ gl_out)
{
    const int p = blockIdx.x;
    // group bmax: handled in fused tail iff <= ATH
    int gbm = 0;
#pragma unroll
    for (int k = 0; k < BPB; ++k)
        gbm = max(gbm, lengths[perm[(p & ~(BPB - 1)) + k]]);
    if (gbm <= ATH) return;        // uniform across block: safe early-exit

    __shared__ float salpha[T_];
    __shared__ float shT[DH_];
    __shared__ float sQ[DH_];
    __shared__ float sqk[DH_];
    __shared__ float spart[DH_];
    __shared__ float sfeats[2 * DH_];
    __shared__ float sh1[2][DH_];
    __shared__ float sred[4], ssum[4];
    __shared__ float sgl[E_];
    __shared__ float spi[2];
    __shared__ float souts[2];
    __shared__ float sqb_s;
    __shared__ int stopi[2];

    const int b = perm[p];
    const int tid = threadIdx.x;
    const int len = lengths[b];
    const float scale = 0.10206207262f; // 1/sqrt(96)

    // ---- fused qk: Q = Wq@hT + bq; qk = (Wk^T Q)*scale; qb = (Q.bk)*scale
    if (tid < DH_) shT[tid] = hT[b * DH_ + tid];
    __syncthreads();
    if (tid < DH_) {
        float acc = bq[tid];
        const float* wr = Wq + tid * DH_;
        for (int d = 0; d < DH_; d += 4) {
            float4 w4 = *(const float4*)(wr + d);
            acc += w4.x * shT[d] + w4.y * shT[d + 1] + w4.z * shT[d + 2] + w4.w * shT[d + 3];
        }
        sQ[tid] = acc;
    }
    __syncthreads();
    if (tid < DH_) {
        float acc = 0.f;
        for (int j = 0; j < DH_; ++j) acc += Wk[j * DH_ + tid] * sQ[j];
        sqk[tid] = acc * scale;
    }
    if (tid >= 192) {                 // wave 3 computes qb in parallel
        const int ln = tid - 192;
        float pq = sQ[ln] * bk[ln];
        if (ln < DH_ - 64) pq += sQ[ln + 64] * bk[ln + 64];
        for (int off = 32; off; off >>= 1) pq += __shfl_xor(pq, off);
        if (ln == 0) sqb_s = pq * scale;
    }
    __syncthreads();
    const float qbv = sqb_s;

    // logits: 2 t's per thread (t = tid, tid+256)
    float lg[2]; bool vd[2];
#pragma unroll
    for (int hh = 0; hh < 2; ++hh) {
        const int t = tid + hh * 256;
        vd[hh] = t < len;
        float l = qbv;
        if (vd[hh]) {
            const _Float16* hr = H + ((long long)b * T_ + t) * DH_;
#pragma unroll
            for (int u = 0; u < DH_; u += 8) {
                f16x8 hv = *(const f16x8*)(hr + u);
                float4 qa = *(const float4*)&sqk[u];
                float4 qc = *(const float4*)&sqk[u + 4];
                l += (float)hv[0] * qa.x + (float)hv[1] * qa.y
                   + (float)hv[2] * qa.z + (float)hv[3] * qa.w
                   + (float)hv[4] * qc.x + (float)hv[5] * qc.y
                   + (float)hv[6] * qc.z + (float)hv[7] * qc.w;
            }
        }
        lg[hh] = l;
    }

    float m = fmaxf(vd[0] ? lg[0] : -1e30f, vd[1] ? lg[1] : -1e30f);
    for (int off = 32; off; off >>= 1) m = fmaxf(m, __shfl_xor(m, off));
    if ((tid & 63) == 0) sred[tid >> 6] = m;
    __syncthreads();
    m = fmaxf(fmaxf(sred[0], sred[1]), fmaxf(sred[2], sred[3]));

    float e0 = vd[0] ? EXP2F((lg[0] - m) * 1.44269504f) : 0.f;
    float e1 = vd[1] ? EXP2F((lg[1] - m) * 1.44269504f) : 0.f;
    float s = e0 + e1;
    for (int off = 32; off; off >>= 1) s += __shfl_xor(s, off);
    if ((tid & 63) == 0) ssum[tid >> 6] = s;
    __syncthreads();
    s = (ssum[0] + ssum[1]) + (ssum[2] + ssum[3]);

    const float rinv = RCPF(s);
    const float a0 = e0 * rinv, a1 = e1 * rinv;
    salpha[tid] = a0;
    salpha[tid + 256] = a1;
    alpha_out[(long long)b * T_ + tid] = a0;
    alpha_out[(long long)b * T_ + tid + 256] = a1;
    __syncthreads();

    // ctx raw: 12 u-blocks x 16 t-lanes, f16x8 loads, shfl-tree reduce over tl
    if (tid < 192) {
        const int ub = tid >> 4, tl = tid & 15;
        float acc[8] = {0.f, 0.f, 0.f, 0.f, 0.f, 0.f, 0.f, 0.f};
        const _Float16* hb = H + ((long long)b * T_) * DH_ + ub * 8;
#pragma unroll 4
        for (int k = 0; k < 32; ++k) {
            const int t = tl + (k << 4);
            if (t < len) {
                f16x8 hv = *(const f16x8*)(hb + t * DH_);
                const float a = salpha[t];
#pragma unroll
                for (int i = 0; i < 8; ++i) acc[i] += a * (float)hv[i];
            }
        }
#pragma unroll
        for (int i = 0; i < 8; ++i) {
            acc[i] += __shfl_xor(acc[i], 1);
            acc[i] += __shfl_xor(acc[i], 2);
            acc[i] += __shfl_xor(acc[i], 4);
            acc[i] += __shfl_xor(acc[i], 8);
        }
        if (tl == 0) {
#pragma unroll
            for (int i = 0; i < 8; ++i) spart[ub * 8 + i] = acc[i];
        }
    }
    __syncthreads();

    // ctx = Wv @ craw + bv ; feats = [ctx, hT]
    if (tid < DH_) {
        float acc = bv[tid];
        const float* wr = Wv + tid * DH_;
        for (int u = 0; u < DH_; u += 4) {
            float4 w4 = *(const float4*)(wr + u);
            acc += w4.x * spart[u] + w4.y * spart[u + 1] + w4.z * spart[u + 2] + w4.w * spart[u + 3];
        }
        sfeats[tid] = acc;             // ctx
        sfeats[DH_ + tid] = shT[tid];  // hT (already in LDS)
    }
    __syncthreads();

    // gate logits: 6 experts x 32 lanes, 6 f-elems per lane
    if (tid < 192) {
        const int e6 = tid >> 5, cc = tid & 31;
        float pq = 0.f;
        const float* wg = Wg + e6 * 2 * DH_;
#pragma unroll
        for (int j = 0; j < 6; ++j) pq += wg[cc * 6 + j] * sfeats[cc * 6 + j];
        for (int off = 16; off; off >>= 1) pq += __shfl_xor(pq, off);
        if (cc == 0) {
            float g = pq + bg[e6];
            sgl[e6] = g;
            gl_out[b * E_ + e6] = g;
        }
    }
    __syncthreads();

    if (tid == 0) {
        int i0 = 0; float v0 = sgl[0];
        for (int ee = 1; ee < E_; ++ee) if (sgl[ee] > v0) { v0 = sgl[ee]; i0 = ee; }
        int i1 = -1; float v1 = -1e30f;
        for (int ee = 0; ee < E_; ++ee) {
            if (ee == i0) continue;
            if (sgl[ee] > v1) { v1 = sgl[ee]; i1 = ee; }
        }
        float ex1 = EXP2F((v1 - v0) * 1.44269504f);
        float inv = RCPF(1.f + ex1);
        spi[0] = inv; spi[1] = ex1 * inv;
        stopi[0] = i0; stopi[1] = i1;
    }
    __syncthreads();

    // expert hidden for the 2 selected experts
    if (tid < 192) {
        const int e2 = tid / DH_, u = tid - e2 * DH_;
        const int ex = stopi[e2];
        float acc = be1[ex * DH_ + u];
        const float* w = We1 + ((long long)ex * DH_ + u) * (2 * DH_);
        for (int f = 0; f < 2 * DH_; f += 4) {
            float4 w4 = *(const float4*)(w + f);
            acc += w4.x * sfeats[f] + w4.y * sfeats[f + 1] + w4.z * sfeats[f + 2] + w4.w * sfeats[f + 3];
        }
        sh1[e2][u] = fmaxf(acc, 0.f);
    }
    __syncthreads();

    // final expert outputs: one wave per expert
    if (tid < 128) {
        const int e2 = tid >> 6, ln = tid & 63;
        const int ex = stopi[e2];
        const float* w2 = We2 + ex * DH_;
        float pq = sh1[e2][ln] * w2[ln];
        if (ln < DH_ - 64) pq += sh1[e2][ln + 64] * w2[ln + 64];
        for (int off = 32; off; off >>= 1) pq += __shfl_xor(pq, off);
        if (ln == 0) souts[e2] = pq + be2[ex];
    }
    __syncthreads();
    if (tid == 0)
        yhat_out[b] = spi[0] * souts[0] + spi[1] * souts[1];
}

extern "C" void kernel_launch(void* const* d_in, const int* in_sizes, int n_in,
                              void* d_out, int out_size, void* d_ws, size_t ws_size,
                              hipStream_t stream) {
    const float* x   = (const float*)d_in[0];
    const int* lengths = (const int*)d_in[1];
    // d_in[2] = mask (recomputed from lengths)
    const float* Wih = (const float*)d_in[3];
    const float* Whh = (const float*)d_in[4];
    const float* bih = (const float*)d_in[5];
    const float* bhh = (const float*)d_in[6];
    const float* Wq  = (const float*)d_in[7];
    const float* bq  = (const float*)d_in[8];
    const float* Wk  = (const float*)d_in[9];
    const float* bk  = (const float*)d_in[10];
    const float* Wv  = (const float*)d_in[11];
    const float* bv  = (const float*)d_in[12];
    const float* Wg  = (const float*)d_in[13];
    const float* bg  = (const float*)d_in[14];
    const float* We1 = (const float*)d_in[15];
    const float* be1 = (const float*)d_in[16];
    const float* We2 = (const float*)d_in[17];
    const float* be2 = (const float*)d_in[18];

    float* yhat  = (float*)d_out;
    float* alpha = yhat + B_;
    float* gl    = alpha + (size_t)B_ * T_;

    char* ws = (char*)d_ws;
    _Float16* Hws = (_Float16*)ws;                                   // B*T*96 fp16
    float* hTws = (float*)(ws + (size_t)B_ * T_ * DH_ * 2);          // B*96 f32
    int* perm   = (int*)(hTws + (size_t)B_ * DH_);                   // B

    sort_kernel<<<dim3(1), dim3(512), 0, stream>>>(lengths, perm);

    lstm_attn_kernel<<<dim3(B_ / BPB), dim3(768), 0, stream>>>(
        x, lengths, perm, Wih, Whh, bih, bhh,
        Wq, bq, Wk, bk, Wv, bv, Wg, bg, We1, be1, We2, be2,
        Hws, hTws, yhat, alpha, gl);

    attn_moe_kernel<<<dim3(B_), dim3(256), 0, stream>>>(
        Hws, hTws, lengths, perm, Wq, bq, Wk, bk, Wv, bv, Wg, bg,
        We1, be1, We2, be2, yhat, alpha, gl);
}